// Round 1
// baseline (1019.429 us; speedup 1.0000x reference)
//
#include <hip/hip_runtime.h>

typedef short short8 __attribute__((ext_vector_type(8)));
typedef float f32x4 __attribute__((ext_vector_type(4)));

#define BATCH 32
#define DIM 192
#define RES 64
#define HW 4096
#define NH 4
#define DH 48
#define NWIN 16
#define LTOK 256
#define BUFE (BATCH * DIM * HW)  // 25,165,824 elems per bf16 buffer
#define SCALE_Q 0.14433756729740643f

__device__ __forceinline__ unsigned short f2bf(float f) {
  unsigned int u = __builtin_bit_cast(unsigned int, f);
  u += 0x7fffu + ((u >> 16) & 1u);
  return (unsigned short)(u >> 16);
}
__device__ __forceinline__ float bf2f(unsigned short h) {
  unsigned int u = ((unsigned int)h) << 16;
  return __builtin_bit_cast(float, u);
}
__device__ __forceinline__ f32x4 mfma16(short8 a, short8 b, f32x4 c) {
  return __builtin_amdgcn_mfma_f32_16x16x32_bf16(a, b, c, 0, 0, 0);
}

// ---------------------------------------------------------------------------
// K1: 1x1 convs as bf16 MFMA GEMM.  Out[576][4096] = W[576][192] @ X[192][4096]
// per batch. oc tile 96, pix tile 64, K=192 fully in LDS.
// oc 0..191 -> q_raw, 192..383 -> k_raw, 384..575 -> v  (all NCHW bf16)
// ---------------------------------------------------------------------------
__global__ __launch_bounds__(256, 2) void k1_conv1x1(
    const float* __restrict__ x, const float* __restrict__ w_qk,
    const float* __restrict__ b_qk, const float* __restrict__ w_v,
    const float* __restrict__ b_v, unsigned short* __restrict__ q_raw,
    unsigned short* __restrict__ k_raw, unsigned short* __restrict__ v_buf) {
  __shared__ unsigned short Al[96 * 200];  // [oc][ic], stride 200 (pad -> 2-way reads)
  __shared__ unsigned short Bl[64 * 200];  // [pix][ic] (transposed)
  const int tid = threadIdx.x;
  const int octile = blockIdx.x;   // 0..5
  const int pixtile = blockIdx.y;  // 0..63
  const int b = blockIdx.z;
  const int oc0 = octile * 96;
  const int pix0 = pixtile * 64;

  // stage A: 96 x 192 weights fp32 -> bf16
  {
    const float* wsrc = (oc0 < 384) ? (w_qk + oc0 * DIM) : (w_v + (oc0 - 384) * DIM);
    for (int it = 0; it < 18; ++it) {
      int u = it * 256 + tid;  // < 4608
      int oc = u / 48, ic4 = u % 48;
      float4 f = *(const float4*)(wsrc + oc * DIM + ic4 * 4);
      uint2 pk;
      pk.x = (unsigned int)f2bf(f.x) | ((unsigned int)f2bf(f.y) << 16);
      pk.y = (unsigned int)f2bf(f.z) | ((unsigned int)f2bf(f.w) << 16);
      *(uint2*)&Al[oc * 200 + ic4 * 4] = pk;
    }
  }
  // stage B: x tile [192 ic][64 pix] fp32, transposed into LDS as [pix][ic] bf16
  {
    const float* xb = x + (size_t)b * (DIM * HW) + pix0;
    int px = tid & 63;
    int icq = tid >> 6;  // 0..3
    for (int it = 0; it < 6; ++it) {
      int ic8 = icq + it * 4;  // 0..23
      const float* p = xb + (size_t)(ic8 * 8) * HW + px;
      unsigned short h[8];
#pragma unroll
      for (int j = 0; j < 8; ++j) h[j] = f2bf(p[(size_t)j * HW]);
      uint4 pk;
      pk.x = h[0] | ((unsigned int)h[1] << 16);
      pk.y = h[2] | ((unsigned int)h[3] << 16);
      pk.z = h[4] | ((unsigned int)h[5] << 16);
      pk.w = h[6] | ((unsigned int)h[7] << 16);
      *(uint4*)&Bl[px * 200 + ic8 * 8] = pk;
    }
  }
  __syncthreads();

  const int lane = tid & 63, wv = tid >> 6;
  const int quad = lane >> 4, col = lane & 15;
  const int m0 = (wv >> 1) * 48, n0 = (wv & 1) * 32;

  f32x4 acc[3][2];
#pragma unroll
  for (int fm = 0; fm < 3; ++fm)
#pragma unroll
    for (int fn = 0; fn < 2; ++fn) {
      acc[fm][fn][0] = 0.f; acc[fm][fn][1] = 0.f;
      acc[fm][fn][2] = 0.f; acc[fm][fn][3] = 0.f;
    }

#pragma unroll
  for (int ks = 0; ks < 6; ++ks) {
    short8 a[3], bb[2];
#pragma unroll
    for (int fm = 0; fm < 3; ++fm)
      a[fm] = *(const short8*)&Al[(m0 + fm * 16 + col) * 200 + ks * 32 + quad * 8];
#pragma unroll
    for (int fn = 0; fn < 2; ++fn)
      bb[fn] = *(const short8*)&Bl[(n0 + fn * 16 + col) * 200 + ks * 32 + quad * 8];
#pragma unroll
    for (int fm = 0; fm < 3; ++fm)
#pragma unroll
      for (int fn = 0; fn < 2; ++fn) acc[fm][fn] = mfma16(a[fm], bb[fn], acc[fm][fn]);
  }

  // epilogue: bias + bf16 store (D: row=oc=quad*4+r, col=pix=lane&15)
  unsigned short* dst;
  int ocbase;
  if (oc0 < 192) { dst = q_raw; ocbase = oc0; }
  else if (oc0 < 384) { dst = k_raw; ocbase = oc0 - 192; }
  else { dst = v_buf; ocbase = oc0 - 384; }
#pragma unroll
  for (int fm = 0; fm < 3; ++fm) {
#pragma unroll
    for (int r = 0; r < 4; ++r) {
      int ocoff = m0 + fm * 16 + quad * 4 + r;
      int ocg = oc0 + ocoff;
      float bias = (ocg < 384) ? b_qk[ocg] : b_v[ocg - 384];
      size_t rowoff = ((size_t)b * DIM + (ocbase + ocoff)) * HW;
#pragma unroll
      for (int fn = 0; fn < 2; ++fn) {
        int pix = pix0 + n0 + fn * 16 + col;
        dst[rowoff + pix] = f2bf(acc[fm][fn][r] + bias);
      }
    }
  }
}

// ---------------------------------------------------------------------------
// K2: cape = depthwise5x5(v) + b_cape  -> d_out (fp32 NCHW)
// ---------------------------------------------------------------------------
__global__ __launch_bounds__(256) void k2_cape(
    const unsigned short* __restrict__ v_buf, const float* __restrict__ w_cape,
    const float* __restrict__ b_cape, float* __restrict__ cape_out) {
  const int c = blockIdx.y, b = blockIdx.z;
  const int h = blockIdx.x * 16 + (threadIdx.x >> 4);
  const int w4 = threadIdx.x & 15;
  const unsigned short* vp = v_buf + ((size_t)b * DIM + c) * HW;
  float wk[25];
#pragma unroll
  for (int i = 0; i < 25; ++i) wk[i] = w_cape[c * 25 + i];
  float acc[4];
  float bz = b_cape[c];
  acc[0] = acc[1] = acc[2] = acc[3] = bz;
#pragma unroll
  for (int dy = 0; dy < 5; ++dy) {
    int hr = h + dy - 2;
    float row[8];
    if (hr >= 0 && hr < RES) {
      const unsigned short* rp = vp + hr * RES + w4 * 4 - 2;
#pragma unroll
      for (int j = 0; j < 4; ++j) {
        int wc = w4 * 4 - 2 + 2 * j;
        unsigned int d = (wc >= 0 && wc < RES) ? *(const unsigned int*)(rp + 2 * j) : 0u;
        row[2 * j] = bf2f((unsigned short)(d & 0xffff));
        row[2 * j + 1] = bf2f((unsigned short)(d >> 16));
      }
    } else {
#pragma unroll
      for (int j = 0; j < 8; ++j) row[j] = 0.f;
    }
#pragma unroll
    for (int wj = 0; wj < 4; ++wj)
#pragma unroll
      for (int dx = 0; dx < 5; ++dx) acc[wj] += row[wj + dx] * wk[dy * 5 + dx];
  }
  float4 o;
  o.x = acc[0]; o.y = acc[1]; o.z = acc[2]; o.w = acc[3];
  *(float4*)&cape_out[((size_t)b * DIM + c) * HW + h * RES + w4 * 4] = o;
}

// ---------------------------------------------------------------------------
// K3/K4: qf/kf = (depthwise5x5(raw) + bias + cape) * scale, written to
// windowed layout [wi][l][c] bf16 (wi = b*16+wb, l = h*4+wm).
// Block: one (b, wb, 16-h tile, 64-c tile). Thread = (c, hq): 4h x 4wm outputs.
// ---------------------------------------------------------------------------
__global__ __launch_bounds__(256) void k3_dw(
    const unsigned short* __restrict__ src, const float* __restrict__ w5,
    const float* __restrict__ b5, const float* __restrict__ cape,
    unsigned short* __restrict__ dst_w, float scale) {
  __shared__ unsigned short patch[64 * 168];  // [c][20 rows x 8 cols], stride 168
  const int wb = blockIdx.x;  // 0..15
  const int ct = blockIdx.y % 3, ht = blockIdx.y / 3;
  const int b = blockIdx.z;
  const int c0 = ct * 64, h0 = ht * 16;
  const int tid = threadIdx.x;

  // stage patch (zero-padded halo); OOB w pairs align with dwords
  for (int it = 0; it < 5; ++it) {
    int u = it * 256 + tid;  // < 1280
    int c = u / 20, rr = u % 20;
    int hr = h0 - 2 + rr;
    uint4 pk;
    pk.x = pk.y = pk.z = pk.w = 0u;
    if (hr >= 0 && hr < RES) {
      const unsigned short* rp =
          src + ((size_t)b * DIM + c0 + c) * HW + hr * RES + wb * 4 - 2;
      unsigned int dw[4];
#pragma unroll
      for (int j = 0; j < 4; ++j) {
        int wc = wb * 4 - 2 + 2 * j;
        dw[j] = (wc >= 0 && wc < RES) ? *(const unsigned int*)(rp + 2 * j) : 0u;
      }
      pk.x = dw[0]; pk.y = dw[1]; pk.z = dw[2]; pk.w = dw[3];
    }
    *(uint4*)&patch[c * 168 + rr * 8] = pk;
  }
  __syncthreads();

  const int c = tid >> 2, hq = tid & 3;
  float wk[25];
#pragma unroll
  for (int i = 0; i < 25; ++i) wk[i] = w5[(c0 + c) * 25 + i];
  float bz = b5[c0 + c];
  float acc[4][4];
#pragma unroll
  for (int j = 0; j < 4; ++j)
#pragma unroll
    for (int wm = 0; wm < 4; ++wm) acc[j][wm] = bz;

#pragma unroll
  for (int rel = 0; rel < 8; ++rel) {
    int p = hq * 4 + rel;  // 0..19
    uint4 pk = *(const uint4*)&patch[c * 168 + p * 8];
    float f8[8];
    f8[0] = bf2f((unsigned short)(pk.x & 0xffff));
    f8[1] = bf2f((unsigned short)(pk.x >> 16));
    f8[2] = bf2f((unsigned short)(pk.y & 0xffff));
    f8[3] = bf2f((unsigned short)(pk.y >> 16));
    f8[4] = bf2f((unsigned short)(pk.z & 0xffff));
    f8[5] = bf2f((unsigned short)(pk.z >> 16));
    f8[6] = bf2f((unsigned short)(pk.w & 0xffff));
    f8[7] = bf2f((unsigned short)(pk.w >> 16));
#pragma unroll
    for (int j = 0; j < 4; ++j) {
      int dy = rel - j;
      if (dy >= 0 && dy <= 4) {
#pragma unroll
        for (int wm = 0; wm < 4; ++wm)
#pragma unroll
          for (int dx = 0; dx < 5; ++dx) acc[j][wm] += f8[wm + dx] * wk[dy * 5 + dx];
      }
    }
  }

  size_t cpbase = ((size_t)b * DIM + c0 + c) * HW + (size_t)wb * 4;
  size_t dwbase = ((size_t)(b * NWIN + wb) * LTOK) * DIM + c0 + c;
#pragma unroll
  for (int j = 0; j < 4; ++j) {
    int h = h0 + hq * 4 + j;
    float4 cp = *(const float4*)&cape[cpbase + (size_t)h * RES];
    float v0 = (acc[j][0] + cp.x) * scale;
    float v1 = (acc[j][1] + cp.y) * scale;
    float v2 = (acc[j][2] + cp.z) * scale;
    float v3 = (acc[j][3] + cp.w) * scale;
    dst_w[dwbase + (size_t)(h * 4 + 0) * DIM] = f2bf(v0);
    dst_w[dwbase + (size_t)(h * 4 + 1) * DIM] = f2bf(v1);
    dst_w[dwbase + (size_t)(h * 4 + 2) * DIM] = f2bf(v2);
    dst_w[dwbase + (size_t)(h * 4 + 3) * DIM] = f2bf(v3);
  }
}

// ---------------------------------------------------------------------------
// K5: windowed attention, one block per (q-tile 64, head, window).
// S = Q K^T (MFMA), wave-private softmax, P->LDS (A-layout), PV (MFMA),
// out -> windowed bf16 [wi][l][c].
// ---------------------------------------------------------------------------
#define KSTR 56
#define VSTR 256
#define PSTR 264
#define OSTR 50

__global__ __launch_bounds__(256, 2) void k5_attn(
    const unsigned short* __restrict__ qf_w, const unsigned short* __restrict__ kf_w,
    const unsigned short* __restrict__ v_buf, unsigned short* __restrict__ out_w) {
  __shared__ unsigned short smem[30208];     // 60416 B
  unsigned short* Kl = smem;                 // 256 x 56  (28672 B)
  unsigned short* Ql = smem + 14336;         // 64 x 56   (7168 B)
  unsigned short* Vl = smem + 17920;         // 48 x 256  (24576 B), xor-swizzled
  unsigned short* Pl = smem;                 // 64 x 264  (33792 B) overlays K+Q
  float* Ot = (float*)(smem + 17920);        // 64 x 50 fp32 (12800 B) overlays V

  const int qt = blockIdx.x, hd = blockIdx.y, wi = blockIdx.z;
  const int b = wi >> 4, wb = wi & 15;
  const int tid = threadIdx.x, lane = tid & 63, wv = tid >> 6;
  const int quad = lane >> 4, col = lane & 15;

  // stage K [kl][d]
  {
    const unsigned short* ks = kf_w + (size_t)wi * LTOK * DIM + hd * DH;
    for (int it = 0; it < 6; ++it) {
      int u = it * 256 + tid;
      int kl = u / 6, part = u % 6;
      *(uint4*)&Kl[kl * KSTR + part * 8] = *(const uint4*)(ks + (size_t)kl * DIM + part * 8);
    }
  }
  // stage Q [ql][d]
  {
    const unsigned short* qs = qf_w + ((size_t)wi * LTOK + qt * 64) * DIM + hd * DH;
    for (int it = 0; it < 2; ++it) {
      int uu = it * 256 + tid;
      if (uu < 384) {
        int ql = uu / 6, part = uu % 6;
        *(uint4*)&Ql[ql * KSTR + part * 8] =
            *(const uint4*)(qs + (size_t)ql * DIM + part * 8);
      }
    }
  }
  // stage V [d][kl] with xor swizzle (kl8 ^= d&7) for conflict-free b128
  {
    const unsigned short* vs = v_buf + ((size_t)b * DIM + hd * DH) * HW + wb * 4;
    for (int it = 0; it < 12; ++it) {
      int u = it * 256 + tid;
      int d = u >> 6, h = u & 63;
      int kl8 = h >> 1;
      int off = ((kl8 ^ (d & 7)) * 8) + (h & 1) * 4;
      *(uint2*)&Vl[d * VSTR + off] = *(const uint2*)(vs + (size_t)d * HW + h * RES);
    }
  }
  __syncthreads();

  // ---- Q K^T : wave wv owns ql rows [wv*16, wv*16+16)
  f32x4 s[16];
#pragma unroll
  for (int i = 0; i < 16; ++i) { s[i][0] = 0.f; s[i][1] = 0.f; s[i][2] = 0.f; s[i][3] = 0.f; }
  const int qb = wv * 16;
  {
    short8 a0 = *(const short8*)&Ql[(qb + col) * KSTR + quad * 8];
#pragma unroll
    for (int fn = 0; fn < 16; ++fn) {
      short8 b0 = *(const short8*)&Kl[(fn * 16 + col) * KSTR + quad * 8];
      s[fn] = mfma16(a0, b0, s[fn]);
    }
    // second k-step covers d 32..47; quads 2,3 (d 48..63) zeroed in registers
    short8 z8 = {0, 0, 0, 0, 0, 0, 0, 0};
    short8 a1 = z8;
    if (quad < 2) a1 = *(const short8*)&Ql[(qb + col) * KSTR + 32 + quad * 8];
#pragma unroll
    for (int fn = 0; fn < 16; ++fn) {
      short8 b1 = z8;
      if (quad < 2) b1 = *(const short8*)&Kl[(fn * 16 + col) * KSTR + 32 + quad * 8];
      s[fn] = mfma16(a1, b1, s[fn]);
    }
  }

  // ---- softmax over kl (row ql = qb + quad*4 + r lives in 16 lanes x 16 frags)
  float mx[4], sm[4], inv[4];
#pragma unroll
  for (int r = 0; r < 4; ++r) {
    float m = s[0][r];
#pragma unroll
    for (int fn = 1; fn < 16; ++fn) m = fmaxf(m, s[fn][r]);
    mx[r] = m;
  }
#pragma unroll
  for (int off = 1; off < 16; off <<= 1)
#pragma unroll
    for (int r = 0; r < 4; ++r) mx[r] = fmaxf(mx[r], __shfl_xor(mx[r], off));
#pragma unroll
  for (int r = 0; r < 4; ++r) sm[r] = 0.f;
#pragma unroll
  for (int fn = 0; fn < 16; ++fn)
#pragma unroll
    for (int r = 0; r < 4; ++r) {
      float e = __expf(s[fn][r] - mx[r]);
      s[fn][r] = e;
      sm[r] += e;
    }
#pragma unroll
  for (int off = 1; off < 16; off <<= 1)
#pragma unroll
    for (int r = 0; r < 4; ++r) sm[r] += __shfl_xor(sm[r], off);
#pragma unroll
  for (int r = 0; r < 4; ++r) inv[r] = 1.f / sm[r];

  __syncthreads();  // all waves done reading Kl/Ql; Pl overlays them

  // ---- write P (C-layout -> LDS [ql][kl]), read back in A-layout
#pragma unroll
  for (int fn = 0; fn < 16; ++fn)
#pragma unroll
    for (int r = 0; r < 4; ++r)
      Pl[(qb + quad * 4 + r) * PSTR + fn * 16 + col] = f2bf(s[fn][r] * inv[r]);

  // ---- P V
  f32x4 o[3];
#pragma unroll
  for (int i = 0; i < 3; ++i) { o[i][0] = 0.f; o[i][1] = 0.f; o[i][2] = 0.f; o[i][3] = 0.f; }
#pragma unroll
  for (int ksi = 0; ksi < 8; ++ksi) {
    short8 a = *(const short8*)&Pl[(qb + col) * PSTR + ksi * 32 + quad * 8];
    int kl8 = ksi * 4 + quad;
#pragma unroll
    for (int fn = 0; fn < 3; ++fn) {
      int d = fn * 16 + col;
      short8 bb = *(const short8*)&Vl[d * VSTR + ((kl8 ^ (d & 7)) * 8)];
      o[fn] = mfma16(a, bb, o[fn]);
    }
  }

  __syncthreads();  // all waves done reading Vl; Ot overlays it
#pragma unroll
  for (int fn = 0; fn < 3; ++fn)
#pragma unroll
    for (int r = 0; r < 4; ++r)
      Ot[(qb + quad * 4 + r) * OSTR + fn * 16 + col] = o[fn][r];
  __syncthreads();

  // ---- coalesced-ish windowed store
  {
    unsigned short* dst = out_w + ((size_t)wi * LTOK + qt * 64) * DIM + hd * DH;
    for (int it = 0; it < 3; ++it) {
      int u = it * 256 + tid;
      int l = u / 12, d4 = u % 12;
      float f0 = Ot[l * OSTR + d4 * 4 + 0];
      float f1 = Ot[l * OSTR + d4 * 4 + 1];
      float f2 = Ot[l * OSTR + d4 * 4 + 2];
      float f3 = Ot[l * OSTR + d4 * 4 + 3];
      uint2 pk;
      pk.x = (unsigned int)f2bf(f0) | ((unsigned int)f2bf(f1) << 16);
      pk.y = (unsigned int)f2bf(f2) | ((unsigned int)f2bf(f3) << 16);
      *(uint2*)(dst + (size_t)l * DIM + d4 * 4) = pk;
    }
  }
}

// ---------------------------------------------------------------------------
// K6: windows2img(out_w) + cape -> d_out (fp32 NCHW), LDS transpose for
// fully coalesced float4 output.
// ---------------------------------------------------------------------------
__global__ __launch_bounds__(256) void k6_final(
    const unsigned short* __restrict__ out_w, float* __restrict__ io) {
  __shared__ float tile[16 * 528];  // [c] stride 528, [h] stride 66, [w]
  const int ht = blockIdx.x, ct = blockIdx.y, b = blockIdx.z;  // grid(8,12,32)
  const int c0 = ct * 16, h0 = ht * 8;
  const int tid = threadIdx.x;
  for (int it = 0; it < 8; ++it) {
    int u = it * 256 + tid;  // < 2048
    int c = u & 15, w4 = (u >> 4) & 15, h = u >> 8;
    const unsigned short* p =
        out_w + (((size_t)(b * NWIN + w4) * LTOK) + (size_t)(h0 + h) * 4) * DIM + c0 + c;
#pragma unroll
    for (int wm = 0; wm < 4; ++wm)
      tile[c * 528 + h * 66 + w4 * 4 + wm] = bf2f(p[(size_t)wm * DIM]);
  }
  __syncthreads();
  for (int it = 0; it < 8; ++it) {
    int u = it * 256 + tid;
    int w16 = u & 15, h = (u >> 4) & 7, c = u >> 7;
    size_t g = ((size_t)b * DIM + c0 + c) * HW + (size_t)(h0 + h) * RES + w16 * 4;
    float4 cp = *(const float4*)&io[g];
    float4 ov;
    ov.x = tile[c * 528 + h * 66 + w16 * 4 + 0] + cp.x;
    ov.y = tile[c * 528 + h * 66 + w16 * 4 + 1] + cp.y;
    ov.z = tile[c * 528 + h * 66 + w16 * 4 + 2] + cp.z;
    ov.w = tile[c * 528 + h * 66 + w16 * 4 + 3] + cp.w;
    *(float4*)&io[g] = ov;
  }
}

// ---------------------------------------------------------------------------
extern "C" void kernel_launch(void* const* d_in, const int* in_sizes, int n_in,
                              void* d_out, int out_size, void* d_ws, size_t ws_size,
                              hipStream_t stream) {
  (void)in_sizes; (void)n_in; (void)out_size; (void)ws_size;
  const float* x = (const float*)d_in[0];
  const float* w_qk = (const float*)d_in[1];
  const float* b_qk = (const float*)d_in[2];
  const float* w_q5 = (const float*)d_in[3];
  const float* b_q5 = (const float*)d_in[4];
  const float* w_k5 = (const float*)d_in[5];
  const float* b_k5 = (const float*)d_in[6];
  const float* w_v = (const float*)d_in[7];
  const float* b_v = (const float*)d_in[8];
  const float* w_cape = (const float*)d_in[9];
  const float* b_cape = (const float*)d_in[10];
  float* out = (float*)d_out;

  unsigned short* ws = (unsigned short*)d_ws;
  unsigned short* buf0 = ws;                      // q_raw, later kf_w
  unsigned short* buf1 = ws + (size_t)BUFE;       // k_raw, later out_w
  unsigned short* buf2 = ws + (size_t)BUFE * 2;   // v (NCHW bf16)
  unsigned short* buf3 = ws + (size_t)BUFE * 3;   // qf_w (windowed bf16)

  k1_conv1x1<<<dim3(6, 64, 32), 256, 0, stream>>>(x, w_qk, b_qk, w_v, b_v, buf0, buf1, buf2);
  k2_cape<<<dim3(4, 192, 32), 256, 0, stream>>>(buf2, w_cape, b_cape, out);
  k3_dw<<<dim3(16, 12, 32), 256, 0, stream>>>(buf0, w_q5, b_q5, out, buf3, SCALE_Q);
  k3_dw<<<dim3(16, 12, 32), 256, 0, stream>>>(buf1, w_k5, b_k5, out, buf0, 1.0f);
  k5_attn<<<dim3(4, 4, 512), 256, 0, stream>>>(buf3, buf0, buf2, buf1);
  k6_final<<<dim3(8, 12, 32), 256, 0, stream>>>(buf1, out);
}

// Round 2
// 786.488 us; speedup vs baseline: 1.2962x; 1.2962x over previous
//
#include <hip/hip_runtime.h>

typedef short short8 __attribute__((ext_vector_type(8)));
typedef float f32x4 __attribute__((ext_vector_type(4)));

#define BATCH 32
#define DIM 192
#define RES 64
#define HW 4096
#define NH 4
#define DH 48
#define NWIN 16
#define LTOK 256
#define BUFE (BATCH * DIM * HW)  // 25,165,824 elems per bf16 buffer
#define SCALE_Q 0.14433756729740643f

__device__ __forceinline__ unsigned short f2bf(float f) {
  unsigned int u = __builtin_bit_cast(unsigned int, f);
  u += 0x7fffu + ((u >> 16) & 1u);
  return (unsigned short)(u >> 16);
}
__device__ __forceinline__ float bf2f(unsigned short h) {
  unsigned int u = ((unsigned int)h) << 16;
  return __builtin_bit_cast(float, u);
}
__device__ __forceinline__ f32x4 mfma16(short8 a, short8 b, f32x4 c) {
  return __builtin_amdgcn_mfma_f32_16x16x32_bf16(a, b, c, 0, 0, 0);
}

// ---------------------------------------------------------------------------
// K1: 1x1 convs as bf16 MFMA GEMM.  Out[576][4096] = W[576][192] @ X[192][4096]
// per batch. oc tile 96, pix tile 64, K=192 fully in LDS.  (unchanged r1)
// ---------------------------------------------------------------------------
__global__ __launch_bounds__(256, 2) void k1_conv1x1(
    const float* __restrict__ x, const float* __restrict__ w_qk,
    const float* __restrict__ b_qk, const float* __restrict__ w_v,
    const float* __restrict__ b_v, unsigned short* __restrict__ q_raw,
    unsigned short* __restrict__ k_raw, unsigned short* __restrict__ v_buf) {
  __shared__ unsigned short Al[96 * 200];
  __shared__ unsigned short Bl[64 * 200];
  const int tid = threadIdx.x;
  const int octile = blockIdx.x;
  const int pixtile = blockIdx.y;
  const int b = blockIdx.z;
  const int oc0 = octile * 96;
  const int pix0 = pixtile * 64;

  {
    const float* wsrc = (oc0 < 384) ? (w_qk + oc0 * DIM) : (w_v + (oc0 - 384) * DIM);
    for (int it = 0; it < 18; ++it) {
      int u = it * 256 + tid;
      int oc = u / 48, ic4 = u % 48;
      float4 f = *(const float4*)(wsrc + oc * DIM + ic4 * 4);
      uint2 pk;
      pk.x = (unsigned int)f2bf(f.x) | ((unsigned int)f2bf(f.y) << 16);
      pk.y = (unsigned int)f2bf(f.z) | ((unsigned int)f2bf(f.w) << 16);
      *(uint2*)&Al[oc * 200 + ic4 * 4] = pk;
    }
  }
  {
    const float* xb = x + (size_t)b * (DIM * HW) + pix0;
    int px = tid & 63;
    int icq = tid >> 6;
    for (int it = 0; it < 6; ++it) {
      int ic8 = icq + it * 4;
      const float* p = xb + (size_t)(ic8 * 8) * HW + px;
      unsigned short h[8];
#pragma unroll
      for (int j = 0; j < 8; ++j) h[j] = f2bf(p[(size_t)j * HW]);
      uint4 pk;
      pk.x = h[0] | ((unsigned int)h[1] << 16);
      pk.y = h[2] | ((unsigned int)h[3] << 16);
      pk.z = h[4] | ((unsigned int)h[5] << 16);
      pk.w = h[6] | ((unsigned int)h[7] << 16);
      *(uint4*)&Bl[px * 200 + ic8 * 8] = pk;
    }
  }
  __syncthreads();

  const int lane = tid & 63, wv = tid >> 6;
  const int quad = lane >> 4, col = lane & 15;
  const int m0 = (wv >> 1) * 48, n0 = (wv & 1) * 32;

  f32x4 acc[3][2];
#pragma unroll
  for (int fm = 0; fm < 3; ++fm)
#pragma unroll
    for (int fn = 0; fn < 2; ++fn) {
      acc[fm][fn][0] = 0.f; acc[fm][fn][1] = 0.f;
      acc[fm][fn][2] = 0.f; acc[fm][fn][3] = 0.f;
    }

#pragma unroll
  for (int ks = 0; ks < 6; ++ks) {
    short8 a[3], bb[2];
#pragma unroll
    for (int fm = 0; fm < 3; ++fm)
      a[fm] = *(const short8*)&Al[(m0 + fm * 16 + col) * 200 + ks * 32 + quad * 8];
#pragma unroll
    for (int fn = 0; fn < 2; ++fn)
      bb[fn] = *(const short8*)&Bl[(n0 + fn * 16 + col) * 200 + ks * 32 + quad * 8];
#pragma unroll
    for (int fm = 0; fm < 3; ++fm)
#pragma unroll
      for (int fn = 0; fn < 2; ++fn) acc[fm][fn] = mfma16(a[fm], bb[fn], acc[fm][fn]);
  }

  unsigned short* dst;
  int ocbase;
  if (oc0 < 192) { dst = q_raw; ocbase = oc0; }
  else if (oc0 < 384) { dst = k_raw; ocbase = oc0 - 192; }
  else { dst = v_buf; ocbase = oc0 - 384; }
#pragma unroll
  for (int fm = 0; fm < 3; ++fm) {
#pragma unroll
    for (int r = 0; r < 4; ++r) {
      int ocoff = m0 + fm * 16 + quad * 4 + r;
      int ocg = oc0 + ocoff;
      float bias = (ocg < 384) ? b_qk[ocg] : b_v[ocg - 384];
      size_t rowoff = ((size_t)b * DIM + (ocbase + ocoff)) * HW;
#pragma unroll
      for (int fn = 0; fn < 2; ++fn) {
        int pix = pix0 + n0 + fn * 16 + col;
        dst[rowoff + pix] = f2bf(acc[fm][fn][r] + bias);
      }
    }
  }
}

// ---------------------------------------------------------------------------
// K2: cape = depthwise5x5(v) + b_cape -> d_out (fp32 NCHW)  (unchanged r1)
// ---------------------------------------------------------------------------
__global__ __launch_bounds__(256) void k2_cape(
    const unsigned short* __restrict__ v_buf, const float* __restrict__ w_cape,
    const float* __restrict__ b_cape, float* __restrict__ cape_out) {
  const int c = blockIdx.y, b = blockIdx.z;
  const int h = blockIdx.x * 16 + (threadIdx.x >> 4);
  const int w4 = threadIdx.x & 15;
  const unsigned short* vp = v_buf + ((size_t)b * DIM + c) * HW;
  float wk[25];
#pragma unroll
  for (int i = 0; i < 25; ++i) wk[i] = w_cape[c * 25 + i];
  float acc[4];
  float bz = b_cape[c];
  acc[0] = acc[1] = acc[2] = acc[3] = bz;
#pragma unroll
  for (int dy = 0; dy < 5; ++dy) {
    int hr = h + dy - 2;
    float row[8];
    if (hr >= 0 && hr < RES) {
      const unsigned short* rp = vp + hr * RES + w4 * 4 - 2;
#pragma unroll
      for (int j = 0; j < 4; ++j) {
        int wc = w4 * 4 - 2 + 2 * j;
        unsigned int d = (wc >= 0 && wc < RES) ? *(const unsigned int*)(rp + 2 * j) : 0u;
        row[2 * j] = bf2f((unsigned short)(d & 0xffff));
        row[2 * j + 1] = bf2f((unsigned short)(d >> 16));
      }
    } else {
#pragma unroll
      for (int j = 0; j < 8; ++j) row[j] = 0.f;
    }
#pragma unroll
    for (int wj = 0; wj < 4; ++wj)
#pragma unroll
      for (int dx = 0; dx < 5; ++dx) acc[wj] += row[wj + dx] * wk[dy * 5 + dx];
  }
  float4 o;
  o.x = acc[0]; o.y = acc[1]; o.z = acc[2]; o.w = acc[3];
  *(float4*)&cape_out[((size_t)b * DIM + c) * HW + h * RES + w4 * 4] = o;
}

// ---------------------------------------------------------------------------
// K3/K4: qf/kf = (depthwise5x5(raw) + bias + cape) * scale -> windowed [wi][l][c]
// New: 1D grid w/ XCD swizzle; output staged in LDS, stored as coalesced uint4.
// ---------------------------------------------------------------------------
__global__ __launch_bounds__(256) void k3_dw(
    const unsigned short* __restrict__ src, const float* __restrict__ w5,
    const float* __restrict__ b5, const float* __restrict__ cape,
    unsigned short* __restrict__ dst_w, float scale) {
  __shared__ unsigned short patch[64 * 168];  // [c][20 rows x 8 cols]
  __shared__ unsigned short outS[64 * 72];    // [l_local][c], stride 72
  const int lid = blockIdx.x;  // 6144, XCD-swizzled
  const int xx = lid & 7;
  const int ii = lid >> 3;            // 0..767
  const int b = xx * 4 + ii / 192;    // all blocks of b share XCD xx
  const int rem = ii % 192;
  const int wb = rem / 12;
  const int rr2 = rem % 12;
  const int ct = rr2 >> 2, ht = rr2 & 3;
  const int c0 = ct * 64, h0 = ht * 16;
  const int tid = threadIdx.x;

  for (int it = 0; it < 5; ++it) {
    int u = it * 256 + tid;  // < 1280
    int c = u / 20, rr = u % 20;
    int hr = h0 - 2 + rr;
    uint4 pk;
    pk.x = pk.y = pk.z = pk.w = 0u;
    if (hr >= 0 && hr < RES) {
      const unsigned short* rp =
          src + ((size_t)b * DIM + c0 + c) * HW + hr * RES + wb * 4 - 2;
      unsigned int dw[4];
#pragma unroll
      for (int j = 0; j < 4; ++j) {
        int wc = wb * 4 - 2 + 2 * j;
        dw[j] = (wc >= 0 && wc < RES) ? *(const unsigned int*)(rp + 2 * j) : 0u;
      }
      pk.x = dw[0]; pk.y = dw[1]; pk.z = dw[2]; pk.w = dw[3];
    }
    *(uint4*)&patch[c * 168 + rr * 8] = pk;
  }
  __syncthreads();

  const int c = tid >> 2, hq = tid & 3;
  float wk[25];
#pragma unroll
  for (int i = 0; i < 25; ++i) wk[i] = w5[(c0 + c) * 25 + i];
  float bz = b5[c0 + c];
  float acc[4][4];
#pragma unroll
  for (int j = 0; j < 4; ++j)
#pragma unroll
    for (int wm = 0; wm < 4; ++wm) acc[j][wm] = bz;

#pragma unroll
  for (int rel = 0; rel < 8; ++rel) {
    int p = hq * 4 + rel;
    uint4 pk = *(const uint4*)&patch[c * 168 + p * 8];
    float f8[8];
    f8[0] = bf2f((unsigned short)(pk.x & 0xffff));
    f8[1] = bf2f((unsigned short)(pk.x >> 16));
    f8[2] = bf2f((unsigned short)(pk.y & 0xffff));
    f8[3] = bf2f((unsigned short)(pk.y >> 16));
    f8[4] = bf2f((unsigned short)(pk.z & 0xffff));
    f8[5] = bf2f((unsigned short)(pk.z >> 16));
    f8[6] = bf2f((unsigned short)(pk.w & 0xffff));
    f8[7] = bf2f((unsigned short)(pk.w >> 16));
#pragma unroll
    for (int j = 0; j < 4; ++j) {
      int dy = rel - j;
      if (dy >= 0 && dy <= 4) {
#pragma unroll
        for (int wm = 0; wm < 4; ++wm)
#pragma unroll
          for (int dx = 0; dx < 5; ++dx) acc[j][wm] += f8[wm + dx] * wk[dy * 5 + dx];
      }
    }
  }

  size_t cpbase = ((size_t)b * DIM + c0 + c) * HW + (size_t)wb * 4;
#pragma unroll
  for (int j = 0; j < 4; ++j) {
    int h = h0 + hq * 4 + j;
    float4 cp = *(const float4*)&cape[cpbase + (size_t)h * RES];
    int lb = (hq * 4 + j) * 4;  // l_local base
    outS[(lb + 0) * 72 + c] = f2bf((acc[j][0] + cp.x) * scale);
    outS[(lb + 1) * 72 + c] = f2bf((acc[j][1] + cp.y) * scale);
    outS[(lb + 2) * 72 + c] = f2bf((acc[j][2] + cp.z) * scale);
    outS[(lb + 3) * 72 + c] = f2bf((acc[j][3] + cp.w) * scale);
  }
  __syncthreads();

  // cooperative coalesced store: 64 l_local rows x 64 c
  const size_t obase = ((size_t)(b * NWIN + wb) * LTOK + (size_t)h0 * 4) * DIM + c0;
  for (int it = 0; it < 2; ++it) {
    int u = it * 256 + tid;  // < 512
    int ll = u >> 3, part = u & 7;
    *(uint4*)&dst_w[obase + (size_t)ll * DIM + part * 8] =
        *(const uint4*)&outS[ll * 72 + part * 8];
  }
}

// ---------------------------------------------------------------------------
// K5: windowed attention. NEW: S^T = K·Q^T formulation (softmax row in one
// lane), Q fragments direct from global, P (b64) overlays K in LDS, direct
// global epilogue, 2 barriers, XCD-swizzled 1D grid.
// ---------------------------------------------------------------------------
#define KSTR 56
#define VSTR 256
#define PSTR 264

__global__ __launch_bounds__(256, 2) void k5_attn(
    const unsigned short* __restrict__ qf_w, const unsigned short* __restrict__ kf_w,
    const unsigned short* __restrict__ v_buf, unsigned short* __restrict__ out_w) {
  __shared__ unsigned short smem[29184];  // 58368 B
  unsigned short* Kl = smem;              // [256][56] = 28672 B (dead after QK)
  unsigned short* Pl = smem;              // [64][264] = 33792 B overlays Kl
  unsigned short* Vl = smem + 16896;      // [48][256] = 24576 B, xor-swizzled

  const int lid = blockIdx.x;  // 8192, XCD-swizzled: all blocks of b on XCD lid&7
  const int xx = lid & 7;
  const int ii = lid >> 3;              // 0..1023
  const int b = (xx << 2) | (ii >> 8);  // 0..31
  const int rem = ii & 255;
  const int wb = rem >> 4;
  const int hd = (rem >> 2) & 3;
  const int qt = rem & 3;
  const int wi = b * NWIN + wb;

  const int tid = threadIdx.x, lane = tid & 63, wv = tid >> 6;
  const int quad = lane >> 4, col = lane & 15;
  const int q = qt * 64 + wv * 16 + col;  // this lane's q row (n-index)

  // Q fragments direct from global (issued early to hide latency)
  const unsigned short* qp = qf_w + ((size_t)wi * LTOK + q) * DIM + hd * DH;
  short8 z8 = {0, 0, 0, 0, 0, 0, 0, 0};
  short8 bq0 = *(const short8*)(qp + quad * 8);
  short8 bq1 = z8;
  if (quad < 2) bq1 = *(const short8*)(qp + 32 + quad * 8);

  // stage K [kl][d] stride 56
  {
    const unsigned short* ks = kf_w + (size_t)wi * LTOK * DIM + hd * DH;
    for (int it = 0; it < 6; ++it) {
      int u = it * 256 + tid;
      int kl = u / 6, part = u % 6;
      *(uint4*)&Kl[kl * KSTR + part * 8] = *(const uint4*)(ks + (size_t)kl * DIM + part * 8);
    }
  }
  // stage V^T [d][kl] xor-swizzled (kl8 ^= d&7)
  {
    const unsigned short* vs = v_buf + ((size_t)b * DIM + hd * DH) * HW + wb * 4;
    for (int it = 0; it < 12; ++it) {
      int u = it * 256 + tid;
      int d = u >> 6, h = u & 63;
      int kl8 = h >> 1;
      int off = ((kl8 ^ (d & 7)) * 8) + (h & 1) * 4;
      *(uint2*)&Vl[d * VSTR + off] = *(const uint2*)(vs + (size_t)d * HW + h * RES);
    }
  }
  __syncthreads();

  // ---- S^T = K Q^T : a = K rows (m=kl), b = Q rows (n=q)
  f32x4 s[16];
#pragma unroll
  for (int i = 0; i < 16; ++i) { s[i][0] = 0.f; s[i][1] = 0.f; s[i][2] = 0.f; s[i][3] = 0.f; }
#pragma unroll
  for (int fm = 0; fm < 16; ++fm) {
    short8 a0 = *(const short8*)&Kl[(fm * 16 + col) * KSTR + quad * 8];
    s[fm] = mfma16(a0, bq0, s[fm]);
  }
#pragma unroll
  for (int fm = 0; fm < 16; ++fm) {
    short8 a1 = z8;
    if (quad < 2) a1 = *(const short8*)&Kl[(fm * 16 + col) * KSTR + 32 + quad * 8];
    s[fm] = mfma16(a1, bq1, s[fm]);
  }

  // ---- softmax: row q lives in lanes {col, col+16, col+32, col+48}
  float mx = s[0][0];
#pragma unroll
  for (int fm = 0; fm < 16; ++fm)
#pragma unroll
    for (int r = 0; r < 4; ++r) mx = fmaxf(mx, s[fm][r]);
  mx = fmaxf(mx, __shfl_xor(mx, 16));
  mx = fmaxf(mx, __shfl_xor(mx, 32));
  float sm = 0.f;
#pragma unroll
  for (int fm = 0; fm < 16; ++fm)
#pragma unroll
    for (int r = 0; r < 4; ++r) {
      float e = __expf(s[fm][r] - mx);
      s[fm][r] = e;
      sm += e;
    }
  sm += __shfl_xor(sm, 16);
  sm += __shfl_xor(sm, 32);
  float inv = 1.f / sm;

  __syncthreads();  // all waves done reading Kl; Pl overlays it

  // ---- write P rows (b64 per fm: r=0..3 are kl-consecutive)
  {
    unsigned short* Pw = Pl + (wv * 16 + col) * PSTR;
#pragma unroll
    for (int fm = 0; fm < 16; ++fm) {
      uint2 pk;
      pk.x = (unsigned int)f2bf(s[fm][0] * inv) | ((unsigned int)f2bf(s[fm][1] * inv) << 16);
      pk.y = (unsigned int)f2bf(s[fm][2] * inv) | ((unsigned int)f2bf(s[fm][3] * inv) << 16);
      *(uint2*)&Pw[fm * 16 + quad * 4] = pk;
    }
  }

  // ---- O = P V  (same-wave P readback; compiler inserts lgkmcnt wait)
  f32x4 o[3];
#pragma unroll
  for (int i = 0; i < 3; ++i) { o[i][0] = 0.f; o[i][1] = 0.f; o[i][2] = 0.f; o[i][3] = 0.f; }
#pragma unroll
  for (int ksi = 0; ksi < 8; ++ksi) {
    short8 a = *(const short8*)&Pl[(wv * 16 + col) * PSTR + ksi * 32 + quad * 8];
#pragma unroll
    for (int fn = 0; fn < 3; ++fn) {
      int d = fn * 16 + col;
      short8 bb = *(const short8*)&Vl[d * VSTR + (((ksi * 4 + quad) ^ (d & 7)) * 8)];
      o[fn] = mfma16(a, bb, o[fn]);
    }
  }

  // ---- direct epilogue: C row m = q-within-16 = quad*4+r, col n = d
  {
    unsigned short* dst = out_w + ((size_t)wi * LTOK + qt * 64 + wv * 16) * DIM + hd * DH;
#pragma unroll
    for (int fn = 0; fn < 3; ++fn)
#pragma unroll
      for (int r = 0; r < 4; ++r)
        dst[(size_t)(quad * 4 + r) * DIM + fn * 16 + col] = f2bf(o[fn][r]);
  }
}

// ---------------------------------------------------------------------------
// K6: windows2img(out_w) + cape -> d_out. NEW: uint4 reads (8 c per load).
// ---------------------------------------------------------------------------
__global__ __launch_bounds__(256) void k6_final(
    const unsigned short* __restrict__ out_w, float* __restrict__ io) {
  __shared__ float tile[16 * 528];  // [c]*528 + [h]*66 + [w]
  const int ht = blockIdx.x, ct = blockIdx.y, b = blockIdx.z;  // grid(8,12,32)
  const int c0 = ct * 16, h0 = ht * 8;
  const int tid = threadIdx.x;
  for (int it = 0; it < 4; ++it) {
    int u = it * 256 + tid;  // < 1024 = 16wb x 32l x 2chunks
    int chunk = u & 1, l5 = (u >> 1) & 31, wb = u >> 6;
    const unsigned short* p =
        out_w + ((size_t)(b * NWIN + wb) * LTOK + (size_t)(h0 * 4 + l5)) * DIM + c0 + chunk * 8;
    uint4 pk = *(const uint4*)p;
    int h = l5 >> 2, wm = l5 & 3;
    float* t = &tile[(chunk * 8) * 528 + h * 66 + wb * 4 + wm];
    t[0 * 528] = bf2f((unsigned short)(pk.x & 0xffff));
    t[1 * 528] = bf2f((unsigned short)(pk.x >> 16));
    t[2 * 528] = bf2f((unsigned short)(pk.y & 0xffff));
    t[3 * 528] = bf2f((unsigned short)(pk.y >> 16));
    t[4 * 528] = bf2f((unsigned short)(pk.z & 0xffff));
    t[5 * 528] = bf2f((unsigned short)(pk.z >> 16));
    t[6 * 528] = bf2f((unsigned short)(pk.w & 0xffff));
    t[7 * 528] = bf2f((unsigned short)(pk.w >> 16));
  }
  __syncthreads();
  for (int it = 0; it < 8; ++it) {
    int u = it * 256 + tid;
    int w16 = u & 15, h = (u >> 4) & 7, c = u >> 7;
    size_t g = ((size_t)b * DIM + c0 + c) * HW + (size_t)(h0 + h) * RES + w16 * 4;
    float4 cp = *(const float4*)&io[g];
    float4 ov;
    ov.x = tile[c * 528 + h * 66 + w16 * 4 + 0] + cp.x;
    ov.y = tile[c * 528 + h * 66 + w16 * 4 + 1] + cp.y;
    ov.z = tile[c * 528 + h * 66 + w16 * 4 + 2] + cp.z;
    ov.w = tile[c * 528 + h * 66 + w16 * 4 + 3] + cp.w;
    *(float4*)&io[g] = ov;
  }
}

// ---------------------------------------------------------------------------
extern "C" void kernel_launch(void* const* d_in, const int* in_sizes, int n_in,
                              void* d_out, int out_size, void* d_ws, size_t ws_size,
                              hipStream_t stream) {
  (void)in_sizes; (void)n_in; (void)out_size; (void)ws_size;
  const float* x = (const float*)d_in[0];
  const float* w_qk = (const float*)d_in[1];
  const float* b_qk = (const float*)d_in[2];
  const float* w_q5 = (const float*)d_in[3];
  const float* b_q5 = (const float*)d_in[4];
  const float* w_k5 = (const float*)d_in[5];
  const float* b_k5 = (const float*)d_in[6];
  const float* w_v = (const float*)d_in[7];
  const float* b_v = (const float*)d_in[8];
  const float* w_cape = (const float*)d_in[9];
  const float* b_cape = (const float*)d_in[10];
  float* out = (float*)d_out;

  unsigned short* ws = (unsigned short*)d_ws;
  unsigned short* buf0 = ws;                     // q_raw, later kf_w
  unsigned short* buf1 = ws + (size_t)BUFE;      // k_raw, later out_w
  unsigned short* buf2 = ws + (size_t)BUFE * 2;  // v (NCHW bf16)
  unsigned short* buf3 = ws + (size_t)BUFE * 3;  // qf_w (windowed bf16)

  k1_conv1x1<<<dim3(6, 64, 32), 256, 0, stream>>>(x, w_qk, b_qk, w_v, b_v, buf0, buf1, buf2);
  k2_cape<<<dim3(4, 192, 32), 256, 0, stream>>>(buf2, w_cape, b_cape, out);
  k3_dw<<<dim3(6144), 256, 0, stream>>>(buf0, w_q5, b_q5, out, buf3, SCALE_Q);
  k3_dw<<<dim3(6144), 256, 0, stream>>>(buf1, w_k5, b_k5, out, buf0, 1.0f);
  k5_attn<<<dim3(8192), 256, 0, stream>>>(buf3, buf0, buf2, buf1);
  k6_final<<<dim3(8, 12, 32), 256, 0, stream>>>(buf1, out);
}